// Round 8
// baseline (184.891 us; speedup 1.0000x reference)
//
#include <hip/hip_runtime.h>

// 3-level db4 DWT (zero-padding mode) as composite FIRs applied directly to x.
// child(t) = sum_j DEC[j]*parent(2t+1-j), zero-extended; composition exact.
// R5 mapping (contiguous q per block — best measured) + store-as-you-go to cut
// live accumulators, + __launch_bounds__(256,4) to cap VGPRs at 128 so TWO
// blocks co-reside per CU (R5/R7 had 156 VGPR -> 12 wave slots -> 1 block/CU;
// R7 proved wave-level work concentration is fatal: 66 us, 4.6% occupancy).

typedef float float4n __attribute__((ext_vector_type(4)));

struct Weights {
    float w1h[8];    // level-1 high:  x[2s+1-j]
    float w2h[22];   // level-2 high:  x[4s+3-m], m=2j+k
    float w3h[50];   // level-3 high:  x[8s+7-m], m=4j+2k+l
    float w3l[50];   // level-3 low (approx)
};

constexpr Weights make_weights() {
    constexpr double LO[8] = {
        -0.010597401784997278,  0.032883011666982945,  0.030841381835986965,
        -0.18703481171888114,  -0.02798376941698385,   0.6308807679295904,
         0.7148465705525415,    0.23037781330885523};
    constexpr double HI[8] = {
        -0.23037781330885523,   0.7148465705525415,   -0.6308807679295904,
        -0.02798376941698385,   0.18703481171888114,   0.030841381835986965,
         0.032883011666982945, -0.010597401784997278};
    double a2h[22] = {}, a3h[50] = {}, a3l[50] = {};
    for (int j = 0; j < 8; ++j)
        for (int k = 0; k < 8; ++k)
            a2h[2 * j + k] += HI[j] * LO[k];
    for (int j = 0; j < 8; ++j)
        for (int k = 0; k < 8; ++k)
            for (int l = 0; l < 8; ++l) {
                a3h[4 * j + 2 * k + l] += HI[j] * LO[k] * LO[l];
                a3l[4 * j + 2 * k + l] += LO[j] * LO[k] * LO[l];
            }
    Weights W = {};
    for (int i = 0; i < 8; ++i)  W.w1h[i] = (float)HI[i];
    for (int i = 0; i < 22; ++i) W.w2h[i] = (float)a2h[i];
    for (int i = 0; i < 50; ++i) { W.w3h[i] = (float)a3h[i]; W.w3l[i] = (float)a3l[i]; }
    return W;
}

__device__ __constant__ Weights CW = make_weights();

__device__ __forceinline__ void fma4(float4n& a, float c, const float4n& v) {
    a.x = fmaf(c, v.x, a.x);
    a.y = fmaf(c, v.y, a.y);
    a.z = fmaf(c, v.z, a.z);
    a.w = fmaf(c, v.w, a.w);
}

// Grid: 1024 blocks x 256 threads. b = id&7 (one b-slice per XCD, ~2.1 MB,
// L2-resident), c = id>>3; group g = tid>>5 owns q = c*8+g (contiguous, the
// R5 mapping). Thread owns output rows s = 4q..4q+3 at f4 column f.
__global__ void __launch_bounds__(256, 4) wavelet_fused_kernel(
        const float4n* __restrict__ x, float4n* __restrict__ out) {
    int id = blockIdx.x;
    int b  = id & 7;
    int c  = id >> 3;
    int q  = c * 8 + (threadIdx.x >> 5);   // 0..1023
    int f  = threadIdx.x & 31;

    const float4n* xb = x + (long)b * 4096 * 32 + f;
    const float4n z = {0.f, 0.f, 0.f, 0.f};
    const long CH = 8L * 4096 * 32;
    long base0 = ((long)b * 4096 + 4 * q) * 32 + f;   // row s=4q, channel 0
    float4n hs[4];

    // ---- Level-1 (8-tap, stride 2): rows [8q-6, 8q+7], 14 loads / 4 outputs
    {
        float4n h1[4] = {z, z, z, z};
        if (q <= 512) {
            int rbase = 8 * q - 6;
#pragma unroll
            for (int rr = 0; rr < 14; ++rr) {
                int r = rbase + rr;
                float4n v = ((unsigned)r < 4096u) ? xb[r * 32] : z;
#pragma unroll
                for (int i = 0; i < 4; ++i) {
                    int m = 2 * i + 7 - rr;
                    if (m >= 0 && m < 8) fma4(h1[i], CW.w1h[m], v);
                }
            }
        }
#pragma unroll
        for (int i = 0; i < 4; ++i) {
            if (4 * q + i >= 2051) h1[i] = z;
            __builtin_nontemporal_store(h1[i], &out[CH + base0 + i * 32]);   // c1
            hs[i] = h1[i];
        }
    }

    // ---- Level-2 (22-tap, stride 4): rows [16q-18, 16q+15], 34 loads / 4 outputs
    {
        float4n h2[4] = {z, z, z, z};
        if (q <= 257) {
            int rbase = 16 * q - 18;
#pragma unroll
            for (int rr = 0; rr < 34; ++rr) {
                int r = rbase + rr;
                float4n v = ((unsigned)r < 4096u) ? xb[r * 32] : z;
#pragma unroll
                for (int i = 0; i < 4; ++i) {
                    int m = 4 * i + 21 - rr;
                    if (m >= 0 && m < 22) fma4(h2[i], CW.w2h[m], v);
                }
            }
        }
#pragma unroll
        for (int i = 0; i < 4; ++i) {
            if (4 * q + i >= 1029) h2[i] = z;
            __builtin_nontemporal_store(h2[i], &out[2 * CH + base0 + i * 32]); // c2
            hs[i] += h2[i];
        }
    }

    // ---- Level-3 (50-tap h+l, stride 8): rows [32q-42, 32q+31], 74 loads / 4 outputs
    {
        float4n h3[4] = {z, z, z, z}, l3[4] = {z, z, z, z};
        if (q <= 129) {
            int rbase = 32 * q - 42;
#pragma unroll
            for (int rr = 0; rr < 74; ++rr) {
                int r = rbase + rr;
                float4n v = ((unsigned)r < 4096u) ? xb[r * 32] : z;
#pragma unroll
                for (int i = 0; i < 4; ++i) {
                    int m = 8 * i + 49 - rr;
                    if (m >= 0 && m < 50) { fma4(h3[i], CW.w3h[m], v); fma4(l3[i], CW.w3l[m], v); }
                }
            }
        }
#pragma unroll
        for (int i = 0; i < 4; ++i) {
            if (4 * q + i >= 518) { h3[i] = z; l3[i] = z; }
            float4n s4 = hs[i] + h3[i];
            __builtin_nontemporal_store(l3[i], &out[base0 + i * 32]);          // c0
            __builtin_nontemporal_store(h3[i], &out[3 * CH + base0 + i * 32]); // c3
            __builtin_nontemporal_store(s4,    &out[4 * CH + base0 + i * 32]); // c4
            __builtin_nontemporal_store(l3[i], &out[5 * CH + base0 + i * 32]); // c5
        }
    }
}

extern "C" void kernel_launch(void* const* d_in, const int* in_sizes, int n_in,
                              void* d_out, int out_size, void* d_ws, size_t ws_size,
                              hipStream_t stream) {
    const float4n* x   = (const float4n*)d_in[0];   // [8, 4096, 128] f32
    float4n*       out = (float4n*)d_out;           // [6, 8, 4096, 128] f32
    wavelet_fused_kernel<<<1024, 256, 0, stream>>>(x, out);
}

// Round 9
// 140.542 us; speedup vs baseline: 1.3156x; 1.3156x over previous
//
#include <hip/hip_runtime.h>

// 3-level db4 DWT (zero-padding mode) as composite FIRs applied directly to x.
// child(t) = sum_j DEC[j]*parent(2t+1-j), zero-extended; composition exact.
// R5 mapping (contiguous q per block — best measured) + store-as-you-go
// (peak live accumulators 8 f4 instead of 16) + __launch_bounds__(256,2):
// VGPR cap 128 -> 2 blocks/CU. R8 proved (256,4)'s 64-VGPR cap spills
// (FETCH 18->58 MB, WRITE 96->168 MB, kernel 95 us); 128 is the right cap.

typedef float float4n __attribute__((ext_vector_type(4)));

struct Weights {
    float w1h[8];    // level-1 high:  x[2s+1-j]
    float w2h[22];   // level-2 high:  x[4s+3-m], m=2j+k
    float w3h[50];   // level-3 high:  x[8s+7-m], m=4j+2k+l
    float w3l[50];   // level-3 low (approx)
};

constexpr Weights make_weights() {
    constexpr double LO[8] = {
        -0.010597401784997278,  0.032883011666982945,  0.030841381835986965,
        -0.18703481171888114,  -0.02798376941698385,   0.6308807679295904,
         0.7148465705525415,    0.23037781330885523};
    constexpr double HI[8] = {
        -0.23037781330885523,   0.7148465705525415,   -0.6308807679295904,
        -0.02798376941698385,   0.18703481171888114,   0.030841381835986965,
         0.032883011666982945, -0.010597401784997278};
    double a2h[22] = {}, a3h[50] = {}, a3l[50] = {};
    for (int j = 0; j < 8; ++j)
        for (int k = 0; k < 8; ++k)
            a2h[2 * j + k] += HI[j] * LO[k];
    for (int j = 0; j < 8; ++j)
        for (int k = 0; k < 8; ++k)
            for (int l = 0; l < 8; ++l) {
                a3h[4 * j + 2 * k + l] += HI[j] * LO[k] * LO[l];
                a3l[4 * j + 2 * k + l] += LO[j] * LO[k] * LO[l];
            }
    Weights W = {};
    for (int i = 0; i < 8; ++i)  W.w1h[i] = (float)HI[i];
    for (int i = 0; i < 22; ++i) W.w2h[i] = (float)a2h[i];
    for (int i = 0; i < 50; ++i) { W.w3h[i] = (float)a3h[i]; W.w3l[i] = (float)a3l[i]; }
    return W;
}

__device__ __constant__ Weights CW = make_weights();

__device__ __forceinline__ void fma4(float4n& a, float c, const float4n& v) {
    a.x = fmaf(c, v.x, a.x);
    a.y = fmaf(c, v.y, a.y);
    a.z = fmaf(c, v.z, a.z);
    a.w = fmaf(c, v.w, a.w);
}

// Grid: 1024 blocks x 256 threads. b = id&7 (one b-slice per XCD, ~2.1 MB,
// L2-resident), c = id>>3; group g = tid>>5 owns q = c*8+g (contiguous, the
// R5 mapping). Thread owns output rows s = 4q..4q+3 at f4 column f.
__global__ void __launch_bounds__(256, 2) wavelet_fused_kernel(
        const float4n* __restrict__ x, float4n* __restrict__ out) {
    int id = blockIdx.x;
    int b  = id & 7;
    int c  = id >> 3;
    int q  = c * 8 + (threadIdx.x >> 5);   // 0..1023
    int f  = threadIdx.x & 31;

    const float4n* xb = x + (long)b * 4096 * 32 + f;
    const float4n z = {0.f, 0.f, 0.f, 0.f};
    const long CH = 8L * 4096 * 32;
    long base0 = ((long)b * 4096 + 4 * q) * 32 + f;   // row s=4q, channel 0
    float4n hs[4];

    // ---- Level-1 (8-tap, stride 2): rows [8q-6, 8q+7], 14 loads / 4 outputs
    {
        float4n h1[4] = {z, z, z, z};
        if (q <= 512) {
            int rbase = 8 * q - 6;
#pragma unroll
            for (int rr = 0; rr < 14; ++rr) {
                int r = rbase + rr;
                float4n v = ((unsigned)r < 4096u) ? xb[r * 32] : z;
#pragma unroll
                for (int i = 0; i < 4; ++i) {
                    int m = 2 * i + 7 - rr;
                    if (m >= 0 && m < 8) fma4(h1[i], CW.w1h[m], v);
                }
            }
        }
#pragma unroll
        for (int i = 0; i < 4; ++i) {
            if (4 * q + i >= 2051) h1[i] = z;
            __builtin_nontemporal_store(h1[i], &out[CH + base0 + i * 32]);   // c1
            hs[i] = h1[i];
        }
    }

    // ---- Level-2 (22-tap, stride 4): rows [16q-18, 16q+15], 34 loads / 4 outputs
    {
        float4n h2[4] = {z, z, z, z};
        if (q <= 257) {
            int rbase = 16 * q - 18;
#pragma unroll
            for (int rr = 0; rr < 34; ++rr) {
                int r = rbase + rr;
                float4n v = ((unsigned)r < 4096u) ? xb[r * 32] : z;
#pragma unroll
                for (int i = 0; i < 4; ++i) {
                    int m = 4 * i + 21 - rr;
                    if (m >= 0 && m < 22) fma4(h2[i], CW.w2h[m], v);
                }
            }
        }
#pragma unroll
        for (int i = 0; i < 4; ++i) {
            if (4 * q + i >= 1029) h2[i] = z;
            __builtin_nontemporal_store(h2[i], &out[2 * CH + base0 + i * 32]); // c2
            hs[i] += h2[i];
        }
    }

    // ---- Level-3 (50-tap h+l, stride 8): rows [32q-42, 32q+31], 74 loads / 4 outputs
    {
        float4n h3[4] = {z, z, z, z}, l3[4] = {z, z, z, z};
        if (q <= 129) {
            int rbase = 32 * q - 42;
#pragma unroll
            for (int rr = 0; rr < 74; ++rr) {
                int r = rbase + rr;
                float4n v = ((unsigned)r < 4096u) ? xb[r * 32] : z;
#pragma unroll
                for (int i = 0; i < 4; ++i) {
                    int m = 8 * i + 49 - rr;
                    if (m >= 0 && m < 50) { fma4(h3[i], CW.w3h[m], v); fma4(l3[i], CW.w3l[m], v); }
                }
            }
        }
#pragma unroll
        for (int i = 0; i < 4; ++i) {
            if (4 * q + i >= 518) { h3[i] = z; l3[i] = z; }
            float4n s4 = hs[i] + h3[i];
            __builtin_nontemporal_store(l3[i], &out[base0 + i * 32]);          // c0
            __builtin_nontemporal_store(h3[i], &out[3 * CH + base0 + i * 32]); // c3
            __builtin_nontemporal_store(s4,    &out[4 * CH + base0 + i * 32]); // c4
            __builtin_nontemporal_store(l3[i], &out[5 * CH + base0 + i * 32]); // c5
        }
    }
}

extern "C" void kernel_launch(void* const* d_in, const int* in_sizes, int n_in,
                              void* d_out, int out_size, void* d_ws, size_t ws_size,
                              hipStream_t stream) {
    const float4n* x   = (const float4n*)d_in[0];   // [8, 4096, 128] f32
    float4n*       out = (float4n*)d_out;           // [6, 8, 4096, 128] f32
    wavelet_fused_kernel<<<1024, 256, 0, stream>>>(x, out);
}

// Round 10
// 117.263 us; speedup vs baseline: 1.5767x; 1.1985x over previous
//
#include <hip/hip_runtime.h>

// 3-level db4 DWT (zero-padding mode) as composite FIRs applied directly to x.
// child(t) = sum_j DEC[j]*parent(2t+1-j), zero-extended; composition exact.
// Exact R5 structure (best measured: dur 121.4, kernel ~35 us): contiguous q
// per block, no launch_bounds (156 VGPR -> 3 blocks/CU), batched stores last.
// Single change vs R5: PLAIN stores instead of nontemporal. The 96 MiB output
// fits in the 256 MiB Infinity Cache; nt forced it to HBM inside the kernel
// window and coupled stores into load waits via the shared vmcnt counter.

typedef float float4n __attribute__((ext_vector_type(4)));

struct Weights {
    float w1h[8];    // level-1 high:  x[2s+1-j]
    float w2h[22];   // level-2 high:  x[4s+3-m], m=2j+k
    float w3h[50];   // level-3 high:  x[8s+7-m], m=4j+2k+l
    float w3l[50];   // level-3 low (approx)
};

constexpr Weights make_weights() {
    constexpr double LO[8] = {
        -0.010597401784997278,  0.032883011666982945,  0.030841381835986965,
        -0.18703481171888114,  -0.02798376941698385,   0.6308807679295904,
         0.7148465705525415,    0.23037781330885523};
    constexpr double HI[8] = {
        -0.23037781330885523,   0.7148465705525415,   -0.6308807679295904,
        -0.02798376941698385,   0.18703481171888114,   0.030841381835986965,
         0.032883011666982945, -0.010597401784997278};
    double a2h[22] = {}, a3h[50] = {}, a3l[50] = {};
    for (int j = 0; j < 8; ++j)
        for (int k = 0; k < 8; ++k)
            a2h[2 * j + k] += HI[j] * LO[k];
    for (int j = 0; j < 8; ++j)
        for (int k = 0; k < 8; ++k)
            for (int l = 0; l < 8; ++l) {
                a3h[4 * j + 2 * k + l] += HI[j] * LO[k] * LO[l];
                a3l[4 * j + 2 * k + l] += LO[j] * LO[k] * LO[l];
            }
    Weights W = {};
    for (int i = 0; i < 8; ++i)  W.w1h[i] = (float)HI[i];
    for (int i = 0; i < 22; ++i) W.w2h[i] = (float)a2h[i];
    for (int i = 0; i < 50; ++i) { W.w3h[i] = (float)a3h[i]; W.w3l[i] = (float)a3l[i]; }
    return W;
}

__device__ __constant__ Weights CW = make_weights();

__device__ __forceinline__ void fma4(float4n& a, float c, const float4n& v) {
    a.x = fmaf(c, v.x, a.x);
    a.y = fmaf(c, v.y, a.y);
    a.z = fmaf(c, v.z, a.z);
    a.w = fmaf(c, v.w, a.w);
}

// Grid: 1024 blocks x 256 threads. b = id&7 (one b-slice per XCD, ~2.1 MB),
// c = id>>3; group g = tid>>5 owns q = c*8+g (contiguous). Thread owns output
// rows s = 4q..4q+3 at f4 column f (512 B rows, fully coalesced).
__global__ void __launch_bounds__(256) wavelet_fused_kernel(
        const float4n* __restrict__ x, float4n* __restrict__ out) {
    int id = blockIdx.x;
    int b  = id & 7;
    int c  = id >> 3;
    int q  = c * 8 + (threadIdx.x >> 5);   // 0..1023
    int f  = threadIdx.x & 31;

    const float4n* xb = x + (long)b * 4096 * 32 + f;
    const float4n z = {0.f, 0.f, 0.f, 0.f};
    float4n h1[4] = {z, z, z, z}, h2[4] = {z, z, z, z};
    float4n h3[4] = {z, z, z, z}, l3[4] = {z, z, z, z};

    // Level-3 (50-tap h+l, stride 8): rows [32q-42, 32q+31], 74 loads / 4 outputs
    if (q <= 129) {
        int rbase = 32 * q - 42;
#pragma unroll
        for (int rr = 0; rr < 74; ++rr) {
            int r = rbase + rr;
            float4n v = ((unsigned)r < 4096u) ? xb[r * 32] : z;
#pragma unroll
            for (int i = 0; i < 4; ++i) {
                int m = 8 * i + 49 - rr;           // compile-time per (rr,i)
                if (m >= 0 && m < 50) { fma4(h3[i], CW.w3h[m], v); fma4(l3[i], CW.w3l[m], v); }
            }
        }
    }
    // Level-2 (22-tap, stride 4): rows [16q-18, 16q+15], 34 loads / 4 outputs
    if (q <= 257) {
        int rbase = 16 * q - 18;
#pragma unroll
        for (int rr = 0; rr < 34; ++rr) {
            int r = rbase + rr;
            float4n v = ((unsigned)r < 4096u) ? xb[r * 32] : z;
#pragma unroll
            for (int i = 0; i < 4; ++i) {
                int m = 4 * i + 21 - rr;
                if (m >= 0 && m < 22) fma4(h2[i], CW.w2h[m], v);
            }
        }
    }
    // Level-1 (8-tap, stride 2): rows [8q-6, 8q+7], 14 loads / 4 outputs
    if (q <= 512) {
        int rbase = 8 * q - 6;
#pragma unroll
        for (int rr = 0; rr < 14; ++rr) {
            int r = rbase + rr;
            float4n v = ((unsigned)r < 4096u) ? xb[r * 32] : z;
#pragma unroll
            for (int i = 0; i < 4; ++i) {
                int m = 2 * i + 7 - rr;
                if (m >= 0 && m < 8) fma4(h1[i], CW.w1h[m], v);
            }
        }
    }

    const long CH = 8L * 4096 * 32;
#pragma unroll
    for (int i = 0; i < 4; ++i) {
        int s = 4 * q + i;
        if (s >= 518)  { h3[i] = z; l3[i] = z; }   // beyond coeff length: exact zero
        if (s >= 1029) h2[i] = z;
        if (s >= 2051) h1[i] = z;
        float4n hs = h1[i] + h2[i] + h3[i];
        long base = ((long)b * 4096 + s) * 32 + f;
        // Plain stores: output (96 MiB) fits in the 256 MiB LLC; let the cache
        // absorb the write burst instead of forcing HBM inside the kernel.
        out[base]          = l3[i];   // c0 approx
        out[CH + base]     = h1[i];   // c1 d1
        out[2 * CH + base] = h2[i];   // c2 d2
        out[3 * CH + base] = h3[i];   // c3 d3
        out[4 * CH + base] = hs;      // c4 high_freq
        out[5 * CH + base] = l3[i];   // c5 low_freq
    }
}

extern "C" void kernel_launch(void* const* d_in, const int* in_sizes, int n_in,
                              void* d_out, int out_size, void* d_ws, size_t ws_size,
                              hipStream_t stream) {
    const float4n* x   = (const float4n*)d_in[0];   // [8, 4096, 128] f32
    float4n*       out = (float4n*)d_out;           // [6, 8, 4096, 128] f32
    wavelet_fused_kernel<<<1024, 256, 0, stream>>>(x, out);
}

// Round 11
// 117.066 us; speedup vs baseline: 1.5794x; 1.0017x over previous
//
#include <hip/hip_runtime.h>

// 3-level db4 DWT (zero-padding mode) as composite FIRs applied directly to x.
// child(t) = sum_j DEC[j]*parent(2t+1-j), zero-extended; composition exact.
// R10 base (contiguous q, plain batched stores — best measured, dur 117.3)
// with coarsening reduced x4 -> x2: 8 live f4 accumulators (~96 VGPR -> 5
// blocks/CU vs 3), heavy 50-tap region spread over 2x more waves, load
// chains halved (58/26/10 per level). Load traffic +40% (~+1.5 us of L2 BW)
// traded for 1.7x occupancy and finer-grained balance.

typedef float float4n __attribute__((ext_vector_type(4)));

struct Weights {
    float w1h[8];    // level-1 high:  x[2s+1-j]
    float w2h[22];   // level-2 high:  x[4s+3-m], m=2j+k
    float w3h[50];   // level-3 high:  x[8s+7-m], m=4j+2k+l
    float w3l[50];   // level-3 low (approx)
};

constexpr Weights make_weights() {
    constexpr double LO[8] = {
        -0.010597401784997278,  0.032883011666982945,  0.030841381835986965,
        -0.18703481171888114,  -0.02798376941698385,   0.6308807679295904,
         0.7148465705525415,    0.23037781330885523};
    constexpr double HI[8] = {
        -0.23037781330885523,   0.7148465705525415,   -0.6308807679295904,
        -0.02798376941698385,   0.18703481171888114,   0.030841381835986965,
         0.032883011666982945, -0.010597401784997278};
    double a2h[22] = {}, a3h[50] = {}, a3l[50] = {};
    for (int j = 0; j < 8; ++j)
        for (int k = 0; k < 8; ++k)
            a2h[2 * j + k] += HI[j] * LO[k];
    for (int j = 0; j < 8; ++j)
        for (int k = 0; k < 8; ++k)
            for (int l = 0; l < 8; ++l) {
                a3h[4 * j + 2 * k + l] += HI[j] * LO[k] * LO[l];
                a3l[4 * j + 2 * k + l] += LO[j] * LO[k] * LO[l];
            }
    Weights W = {};
    for (int i = 0; i < 8; ++i)  W.w1h[i] = (float)HI[i];
    for (int i = 0; i < 22; ++i) W.w2h[i] = (float)a2h[i];
    for (int i = 0; i < 50; ++i) { W.w3h[i] = (float)a3h[i]; W.w3l[i] = (float)a3l[i]; }
    return W;
}

__device__ __constant__ Weights CW = make_weights();

__device__ __forceinline__ void fma4(float4n& a, float c, const float4n& v) {
    a.x = fmaf(c, v.x, a.x);
    a.y = fmaf(c, v.y, a.y);
    a.z = fmaf(c, v.z, a.z);
    a.w = fmaf(c, v.w, a.w);
}

// Grid: 2048 blocks x 256 threads. b = id&7 (one b-slice per XCD, ~2.1 MB),
// c = id>>3 in [0,256); group g = tid>>5 owns q = c*8+g (contiguous q in
// [0,2048)). Thread owns output rows s = 2q..2q+1 at f4 column f.
__global__ void __launch_bounds__(256) wavelet_fused_kernel(
        const float4n* __restrict__ x, float4n* __restrict__ out) {
    int id = blockIdx.x;
    int b  = id & 7;
    int c  = id >> 3;
    int q  = c * 8 + (threadIdx.x >> 5);   // 0..2047
    int f  = threadIdx.x & 31;

    const float4n* xb = x + (long)b * 4096 * 32 + f;
    const float4n z = {0.f, 0.f, 0.f, 0.f};
    float4n h1[2] = {z, z}, h2[2] = {z, z}, h3[2] = {z, z}, l3[2] = {z, z};

    // Level-3 (50-tap h+l, stride 8): rows [16q-42, 16q+15], 58 loads / 2 outputs
    if (q <= 259) {
        int rbase = 16 * q - 42;
#pragma unroll
        for (int rr = 0; rr < 58; ++rr) {
            int r = rbase + rr;
            float4n v = ((unsigned)r < 4096u) ? xb[r * 32] : z;
#pragma unroll
            for (int i = 0; i < 2; ++i) {
                int m = 8 * i + 49 - rr;           // compile-time per (rr,i)
                if (m >= 0 && m < 50) { fma4(h3[i], CW.w3h[m], v); fma4(l3[i], CW.w3l[m], v); }
            }
        }
    }
    // Level-2 (22-tap, stride 4): rows [8q-18, 8q+7], 26 loads / 2 outputs
    if (q <= 514) {
        int rbase = 8 * q - 18;
#pragma unroll
        for (int rr = 0; rr < 26; ++rr) {
            int r = rbase + rr;
            float4n v = ((unsigned)r < 4096u) ? xb[r * 32] : z;
#pragma unroll
            for (int i = 0; i < 2; ++i) {
                int m = 4 * i + 21 - rr;
                if (m >= 0 && m < 22) fma4(h2[i], CW.w2h[m], v);
            }
        }
    }
    // Level-1 (8-tap, stride 2): rows [4q-6, 4q+3], 10 loads / 2 outputs
    if (q <= 1025) {
        int rbase = 4 * q - 6;
#pragma unroll
        for (int rr = 0; rr < 10; ++rr) {
            int r = rbase + rr;
            float4n v = ((unsigned)r < 4096u) ? xb[r * 32] : z;
#pragma unroll
            for (int i = 0; i < 2; ++i) {
                int m = 2 * i + 7 - rr;
                if (m >= 0 && m < 8) fma4(h1[i], CW.w1h[m], v);
            }
        }
    }

    const long CH = 8L * 4096 * 32;
#pragma unroll
    for (int i = 0; i < 2; ++i) {
        int s = 2 * q + i;
        if (s >= 518)  { h3[i] = z; l3[i] = z; }   // beyond coeff length: exact zero
        if (s >= 1029) h2[i] = z;
        if (s >= 2051) h1[i] = z;
        float4n hs = h1[i] + h2[i] + h3[i];
        long base = ((long)b * 4096 + s) * 32 + f;
        // Plain stores: output (96 MiB) fits in the 256 MiB LLC; let the cache
        // absorb the write burst instead of forcing HBM inside the kernel.
        out[base]          = l3[i];   // c0 approx
        out[CH + base]     = h1[i];   // c1 d1
        out[2 * CH + base] = h2[i];   // c2 d2
        out[3 * CH + base] = h3[i];   // c3 d3
        out[4 * CH + base] = hs;      // c4 high_freq
        out[5 * CH + base] = l3[i];   // c5 low_freq
    }
}

extern "C" void kernel_launch(void* const* d_in, const int* in_sizes, int n_in,
                              void* d_out, int out_size, void* d_ws, size_t ws_size,
                              hipStream_t stream) {
    const float4n* x   = (const float4n*)d_in[0];   // [8, 4096, 128] f32
    float4n*       out = (float4n*)d_out;           // [6, 8, 4096, 128] f32
    wavelet_fused_kernel<<<2048, 256, 0, stream>>>(x, out);
}